// Round 2
// baseline (116.198 us; speedup 1.0000x reference)
//
#include <hip/hip_runtime.h>
#include <hip/hip_bf16.h>

#define DEVI __device__ __forceinline__

typedef float f32x4 __attribute__((ext_vector_type(4)));
typedef float float4v __attribute__((ext_vector_type(4)));
typedef __bf16 bf16x8 __attribute__((ext_vector_type(8)));
typedef unsigned short us8 __attribute__((ext_vector_type(8)));

constexpr int NB = 32, TC = 2048, TQ = 256, DD = 256;
constexpr float VNEG = -1e29f;

DEVI unsigned short f2bf(float f) {
  unsigned u = __builtin_bit_cast(unsigned, f);
  u += 0x7FFFu + ((u >> 16) & 1u);   // round-to-nearest-even
  return (unsigned short)(u >> 16);
}
DEVI float bf2f(unsigned short h) {
  return __builtin_bit_cast(float, (unsigned)h << 16);
}

// split x = hi + lo (both bf16); dropping lo*lo keeps products at ~2^-18 rel
DEVI void split8(const float* p, us8& h, us8& l) {
#pragma unroll
  for (int i = 0; i < 8; ++i) {
    const float x = p[i];
    const unsigned short hh = f2bf(x);
    h[i] = hh;
    l[i] = f2bf(x - bf2f(hh));
  }
}

// XOR swizzle on 16B granules within a row; same function on write & read side.
DEVI int swz(int row, int cb) { return cb ^ (((row ^ (cb >> 7)) & 7) << 4); }

DEVI f32x4 mfma16(us8 a, us8 b, f32x4 c) {
  return __builtin_amdgcn_mfma_f32_16x16x32_bf16(
      __builtin_bit_cast(bf16x8, a), __builtin_bit_cast(bf16x8, b), c, 0, 0, 0);
}

// ---------------------------------------------------------------------------
// Kernel A: per (batch, 128-row c-tile):
//   sim = C@Q^T in split-bf16 (hi*hi + hi*lo + lo*hi -> ~fp32 accuracy),
//   masked softmax over q, out1 = P@Q (bf16), row-max M[b,c] for q2c.
// Block: 512 threads = 8 waves as 2 (rows) x 4 (cols); wave tile 64x64.
// ---------------------------------------------------------------------------
__global__ __launch_bounds__(512, 2)
void kA(const float* __restrict__ Cg, const float* __restrict__ Qg,
        const int* __restrict__ clenp, const int* __restrict__ qlenp,
        float* __restrict__ out1, float* __restrict__ Mws)
{
  __shared__ __align__(16) char smem[98304];
  __shared__ float red[512];
  char* const bufChi = smem;           // sim: [128][128B] C chunk hi
  char* const bufClo = smem + 16384;   // sim: [128][128B] C chunk lo
  char* const bufQhi = smem + 32768;   // sim: [256][128B] Q chunk hi
  char* const bufQlo = smem + 65536;   // sim: [256][128B] Q chunk lo
  char* const bufP   = smem;           // PV:  [128][512B] P tile
  char* const bufQt  = smem + 65536;   // PV:  [256][128B] Q^T chunk

  const int id = blockIdx.x;
  const int u = id >> 3;
  const int b = (id & 7) + 8 * (u >> 4);       // batch -> fixed XCD for Q L2 locality
  const int c0 = (u & 15) * 128;

  const int tid = threadIdx.x;
  const int l = tid & 63, wid = tid >> 6;
  const int g = l >> 4, lm = l & 15;
  const int wr = wid >> 2, wc = wid & 3;
  const int clen = clenp[b], qlen = qlenp[b];

  const float* Cb = Cg + (size_t)(b * TC + c0) * DD;
  const float* Qb = Qg + (size_t)b * TQ * DD;

  f32x4 acc[4][4];
#pragma unroll
  for (int mt = 0; mt < 4; ++mt)
#pragma unroll
    for (int nt = 0; nt < 4; ++nt) acc[mt][nt] = (f32x4)0.0f;

  // ---- sim phase: 4 chunks of 64 d ----
  for (int dc = 0; dc < 4; ++dc) {
    {  // stage C chunk [128][64] hi/lo
      const int r = tid >> 2;
      const int dq = (tid & 3) * 16;
      const float* src = Cb + (size_t)r * DD + dc * 64 + dq;
      float v[16];
#pragma unroll
      for (int i = 0; i < 4; ++i) *(float4v*)(v + i * 4) = *(const float4v*)(src + i * 4);
      us8 h0, l0, h1, l1;
      split8(v, h0, l0);
      split8(v + 8, h1, l1);
      const int cb = dq * 2;
      *(us8*)(bufChi + r * 128 + swz(r, cb)) = h0;
      *(us8*)(bufChi + r * 128 + swz(r, cb + 16)) = h1;
      *(us8*)(bufClo + r * 128 + swz(r, cb)) = l0;
      *(us8*)(bufClo + r * 128 + swz(r, cb + 16)) = l1;
    }
    {  // stage Q chunk [256][64] hi/lo
      const int q = tid >> 1;
      const int dq = (tid & 1) * 32;
      const float* src = Qb + (size_t)q * DD + dc * 64 + dq;
      float v[32];
#pragma unroll
      for (int i = 0; i < 8; ++i) *(float4v*)(v + i * 4) = *(const float4v*)(src + i * 4);
      const int cb = dq * 2;
#pragma unroll
      for (int i = 0; i < 4; ++i) {
        us8 h, lo;
        split8(v + i * 8, h, lo);
        *(us8*)(bufQhi + q * 128 + swz(q, cb + i * 16)) = h;
        *(us8*)(bufQlo + q * 128 + swz(q, cb + i * 16)) = lo;
      }
    }
    __syncthreads();
#pragma unroll
    for (int kd = 0; kd < 2; ++kd) {
      us8 ah[4], al[4], bh[4], bl[4];
#pragma unroll
      for (int mt = 0; mt < 4; ++mt) {
        const int row = wr * 64 + mt * 16 + lm;
        ah[mt] = *(const us8*)(bufChi + row * 128 + swz(row, kd * 64 + g * 16));
        al[mt] = *(const us8*)(bufClo + row * 128 + swz(row, kd * 64 + g * 16));
      }
#pragma unroll
      for (int nt = 0; nt < 4; ++nt) {
        const int q = wc * 64 + nt * 16 + lm;
        bh[nt] = *(const us8*)(bufQhi + q * 128 + swz(q, kd * 64 + g * 16));
        bl[nt] = *(const us8*)(bufQlo + q * 128 + swz(q, kd * 64 + g * 16));
      }
#pragma unroll
      for (int mt = 0; mt < 4; ++mt)
#pragma unroll
        for (int nt = 0; nt < 4; ++nt) {
          acc[mt][nt] = mfma16(ah[mt], bh[nt], acc[mt][nt]);
          acc[mt][nt] = mfma16(ah[mt], bl[nt], acc[mt][nt]);
          acc[mt][nt] = mfma16(al[mt], bh[nt], acc[mt][nt]);
        }
    }
    __syncthreads();
  }

  // ---- mask (reproduces reference's fp32 absorption to exactly -1e29) ----
#pragma unroll
  for (int nt = 0; nt < 4; ++nt) {
    const int q = wc * 64 + nt * 16 + lm;
    const bool qm = q >= qlen;
#pragma unroll
    for (int mt = 0; mt < 4; ++mt)
#pragma unroll
      for (int j = 0; j < 4; ++j) {
        const int c = c0 + wr * 64 + mt * 16 + g * 4 + j;
        if (qm || c >= clen) acc[mt][nt][j] = VNEG;
      }
  }

  float rfull[4][4], rsum[4][4];
  // wave-local row max (over this wave's 64 q)
#pragma unroll
  for (int mt = 0; mt < 4; ++mt)
#pragma unroll
    for (int j = 0; j < 4; ++j) {
      float m = fmaxf(fmaxf(acc[mt][0][j], acc[mt][1][j]),
                      fmaxf(acc[mt][2][j], acc[mt][3][j]));
      m = fmaxf(m, __shfl_xor(m, 1, 64));
      m = fmaxf(m, __shfl_xor(m, 2, 64));
      m = fmaxf(m, __shfl_xor(m, 4, 64));
      m = fmaxf(m, __shfl_xor(m, 8, 64));
      rfull[mt][j] = m;
    }
  if (lm == 0) {
#pragma unroll
    for (int mt = 0; mt < 4; ++mt)
#pragma unroll
      for (int j = 0; j < 4; ++j)
        red[wc * 128 + wr * 64 + mt * 16 + g * 4 + j] = rfull[mt][j];
  }
  __syncthreads();
#pragma unroll
  for (int mt = 0; mt < 4; ++mt)
#pragma unroll
    for (int j = 0; j < 4; ++j) {
      const int row = wr * 64 + mt * 16 + g * 4 + j;
      const float m = fmaxf(fmaxf(red[row], red[128 + row]),
                            fmaxf(red[256 + row], red[384 + row]));
      rfull[mt][j] = m;
      if (wc == 0 && lm == 0) Mws[b * TC + c0 + row] = m;  // masked row-max for q2c
    }
  // exp + wave-local partial sums
#pragma unroll
  for (int mt = 0; mt < 4; ++mt)
#pragma unroll
    for (int j = 0; j < 4; ++j) {
      float s = 0.f;
#pragma unroll
      for (int nt = 0; nt < 4; ++nt) {
        const float p = __expf(acc[mt][nt][j] - rfull[mt][j]);
        acc[mt][nt][j] = p;
        s += p;
      }
      s += __shfl_xor(s, 1, 64);
      s += __shfl_xor(s, 2, 64);
      s += __shfl_xor(s, 4, 64);
      s += __shfl_xor(s, 8, 64);
      rsum[mt][j] = s;
    }
  __syncthreads();               // everyone done reading red (max round)
  if (lm == 0) {
#pragma unroll
    for (int mt = 0; mt < 4; ++mt)
#pragma unroll
      for (int j = 0; j < 4; ++j)
        red[wc * 128 + wr * 64 + mt * 16 + g * 4 + j] = rsum[mt][j];
  }
  __syncthreads();
#pragma unroll
  for (int mt = 0; mt < 4; ++mt)
#pragma unroll
    for (int j = 0; j < 4; ++j) {
      const int row = wr * 64 + mt * 16 + g * 4 + j;
      rsum[mt][j] = (red[row] + red[128 + row]) + (red[256 + row] + red[384 + row]);
    }

  // ---- write P (un-normalized exp) as bf16 into bufP (sim buffers dead) ----
#pragma unroll
  for (int mt = 0; mt < 4; ++mt)
#pragma unroll
    for (int nt = 0; nt < 4; ++nt)
#pragma unroll
      for (int j = 0; j < 4; ++j) {
        const int row = wr * 64 + mt * 16 + g * 4 + j;
        const int qc2 = (wc * 64 + nt * 16 + lm) * 2;
        *(unsigned short*)(bufP + row * 512 + swz(row, qc2)) = f2bf(acc[mt][nt][j]);
      }

  // ---- PV phase: out1 = P @ Q, loop 4 chunks of 64 q (Q staged transposed) ----
  f32x4 pacc[4][4];
#pragma unroll
  for (int mt = 0; mt < 4; ++mt)
#pragma unroll
    for (int dt = 0; dt < 4; ++dt) pacc[mt][dt] = (f32x4)0.0f;

  for (int qc = 0; qc < 4; ++qc) {
    {
      const int q = tid & 63;
      const int dp = (tid >> 6) * 32;
      const float* src = Qb + (size_t)(qc * 64 + q) * DD + dp;
      float4v v[8];
#pragma unroll
      for (int i = 0; i < 8; ++i) v[i] = *(const float4v*)(src + i * 4);
#pragma unroll
      for (int i = 0; i < 32; ++i) {
        const int d = dp + i;
        *(unsigned short*)(bufQt + d * 128 + swz(d, q * 2)) = f2bf(v[i >> 2][i & 3]);
      }
    }
    __syncthreads();
#pragma unroll
    for (int kq = 0; kq < 2; ++kq) {
      us8 af[4], bfr[4];
#pragma unroll
      for (int mt = 0; mt < 4; ++mt) {
        const int row = wr * 64 + mt * 16 + lm;
        af[mt] = *(const us8*)(bufP + row * 512 + swz(row, qc * 128 + kq * 64 + g * 16));
      }
#pragma unroll
      for (int dt = 0; dt < 4; ++dt) {
        const int dr = wc * 64 + dt * 16 + lm;
        bfr[dt] = *(const us8*)(bufQt + dr * 128 + swz(dr, kq * 64 + g * 16));
      }
#pragma unroll
      for (int mt = 0; mt < 4; ++mt)
#pragma unroll
        for (int dt = 0; dt < 4; ++dt)
          pacc[mt][dt] = mfma16(af[mt], bfr[dt], pacc[mt][dt]);
    }
    __syncthreads();
  }

  // ---- epilogue: normalize by row sum, store ----
  float inv[4][4];
#pragma unroll
  for (int mt = 0; mt < 4; ++mt)
#pragma unroll
    for (int j = 0; j < 4; ++j) inv[mt][j] = 1.0f / rsum[mt][j];
#pragma unroll
  for (int mt = 0; mt < 4; ++mt) {
#pragma unroll
    for (int j = 0; j < 4; ++j) {
      const size_t rowoff = (size_t)(b * TC + c0 + wr * 64 + mt * 16 + g * 4 + j) * DD;
#pragma unroll
      for (int dt = 0; dt < 4; ++dt)
        out1[rowoff + wc * 64 + dt * 16 + lm] = pacc[mt][dt][j] * inv[mt][j];
    }
  }
}

// ---------------------------------------------------------------------------
// Kernel B1: per-batch max + softmax denominator over M[b, 0..TC)
// ---------------------------------------------------------------------------
__global__ void kB1(const float* __restrict__ Mws, float* __restrict__ bmax,
                    float* __restrict__ bden)
{
  const int b = blockIdx.x, tid = threadIdx.x;
  __shared__ float sred[8];
  const float* Mb = Mws + b * TC;
  float m = -3.4e38f;
  for (int i = tid; i < TC; i += 256) m = fmaxf(m, Mb[i]);
  m = fmaxf(m, __shfl_xor(m, 1, 64));  m = fmaxf(m, __shfl_xor(m, 2, 64));
  m = fmaxf(m, __shfl_xor(m, 4, 64));  m = fmaxf(m, __shfl_xor(m, 8, 64));
  m = fmaxf(m, __shfl_xor(m, 16, 64)); m = fmaxf(m, __shfl_xor(m, 32, 64));
  const int w = tid >> 6;
  if ((tid & 63) == 0) sred[w] = m;
  __syncthreads();
  m = fmaxf(fmaxf(sred[0], sred[1]), fmaxf(sred[2], sred[3]));
  float s = 0.f;
  for (int i = tid; i < TC; i += 256) s += __expf(Mb[i] - m);
  s += __shfl_xor(s, 1, 64);  s += __shfl_xor(s, 2, 64);
  s += __shfl_xor(s, 4, 64);  s += __shfl_xor(s, 8, 64);
  s += __shfl_xor(s, 16, 64); s += __shfl_xor(s, 32, 64);
  if ((tid & 63) == 0) sred[4 + w] = s;
  __syncthreads();
  if (tid == 0) { bmax[b] = m; bden[b] = (sred[4] + sred[5]) + (sred[6] + sred[7]); }
}

// ---------------------------------------------------------------------------
// Kernel B2: part[b,chunk,d] = sum_{c in chunk} softmax(M)[c] * C[b,c,d]
// (deterministic: no atomics; kB3 reduces the 16 chunks)
// ---------------------------------------------------------------------------
__global__ void kB2(const float* __restrict__ Cg, const float* __restrict__ Mws,
                    const float* __restrict__ bmax, const float* __restrict__ bden,
                    float* __restrict__ part)
{
  const int b = blockIdx.x >> 4;
  const int ch = blockIdx.x & 15;
  const int cbase = ch * 128;
  const int tid = threadIdx.x;                // = d
  __shared__ float w[128];
  const float bm = bmax[b];
  const float invd = 1.0f / bden[b];
  if (tid < 128) w[tid] = __expf(Mws[b * TC + cbase + tid] - bm) * invd;
  __syncthreads();
  float acc = 0.f;
  const float* Cb = Cg + (size_t)(b * TC + cbase) * DD + tid;
#pragma unroll 4
  for (int c = 0; c < 128; ++c) acc += w[c] * Cb[(size_t)c * DD];
  part[((size_t)b * 16 + ch) * DD + tid] = acc;
}

__global__ void kB3(const float* __restrict__ part, float* __restrict__ q2c)
{
  const int b = blockIdx.x, d = threadIdx.x;
  float s = 0.f;
#pragma unroll
  for (int ch = 0; ch < 16; ++ch) s += part[((size_t)b * 16 + ch) * DD + d];
  q2c[b * DD + d] = s;
}

// ---------------------------------------------------------------------------
// Kernel C: broadcast q2c[b,d] -> out2[b,c,d]
// ---------------------------------------------------------------------------
__global__ void kC(const float* __restrict__ q2c, float* __restrict__ out2)
{
  const float4v* qv = (const float4v*)q2c;
  float4v* ov = (float4v*)out2;
  const int per = TC * DD / 4;                // float4s per batch
  const size_t total = (size_t)NB * per;
  for (size_t i = (size_t)blockIdx.x * blockDim.x + threadIdx.x; i < total;
       i += (size_t)gridDim.x * blockDim.x) {
    const int bb = (int)(i / per);
    const int d4 = (int)(i & (DD / 4 - 1));
    ov[i] = qv[bb * (DD / 4) + d4];
  }
}

extern "C" void kernel_launch(void* const* d_in, const int* in_sizes, int n_in,
                              void* d_out, int out_size, void* d_ws, size_t ws_size,
                              hipStream_t stream)
{
  const float* Cg = (const float*)d_in[0];
  const float* Qg = (const float*)d_in[1];
  const int* clen = (const int*)d_in[2];
  const int* qlen = (const int*)d_in[3];
  float* out1 = (float*)d_out;
  float* out2 = out1 + (size_t)NB * TC * DD;

  float* Mws = (float*)d_ws;            // [NB*TC]
  float* part = Mws + NB * TC;          // [NB*16*DD]
  float* q2c = part + NB * 16 * DD;     // [NB*DD]
  float* bmax = q2c + NB * DD;          // [NB]
  float* bden = bmax + NB;              // [NB]

  kA<<<dim3(512), dim3(512), 0, stream>>>(Cg, Qg, clen, qlen, out1, Mws);
  kB1<<<dim3(NB), dim3(256), 0, stream>>>(Mws, bmax, bden);
  kB2<<<dim3(NB * 16), dim3(256), 0, stream>>>(Cg, Mws, bmax, bden, part);
  kB3<<<dim3(NB), dim3(256), 0, stream>>>(part, q2c);
  kC<<<dim3(2048), dim3(256), 0, stream>>>(q2c, out2);
}

// Round 3
// 111.791 us; speedup vs baseline: 1.0394x; 1.0394x over previous
//
#include <hip/hip_runtime.h>
#include <hip/hip_bf16.h>

#define DEVI __device__ __forceinline__

typedef float f32x4 __attribute__((ext_vector_type(4)));
typedef float float4v __attribute__((ext_vector_type(4)));
typedef __bf16 bf16x8 __attribute__((ext_vector_type(8)));
typedef unsigned short us8 __attribute__((ext_vector_type(8)));

constexpr int NB = 32, TC = 2048, TQ = 256, DD = 256;
constexpr int CR = 64;                      // c-rows per kA block
constexpr float VNEG = -1e29f;

DEVI unsigned short f2bf(float f) {
  unsigned u = __builtin_bit_cast(unsigned, f);
  u += 0x7FFFu + ((u >> 16) & 1u);   // round-to-nearest-even
  return (unsigned short)(u >> 16);
}
DEVI float bf2f(unsigned short h) {
  return __builtin_bit_cast(float, (unsigned)h << 16);
}

// split x = hi + lo (both bf16); dropping lo*lo keeps products at ~2^-18 rel
DEVI void split8(const float* p, us8& h, us8& l) {
#pragma unroll
  for (int i = 0; i < 8; ++i) {
    const float x = p[i];
    const unsigned short hh = f2bf(x);
    h[i] = hh;
    l[i] = f2bf(x - bf2f(hh));
  }
}

// XOR swizzle on 16B granules within a 512B row; involution (write==read).
DEVI int swz(int row, int cb) { return cb ^ (((row ^ (cb >> 7)) & 7) << 4); }

DEVI f32x4 mfma16(us8 a, us8 b, f32x4 c) {
  return __builtin_amdgcn_mfma_f32_16x16x32_bf16(
      __builtin_bit_cast(bf16x8, a), __builtin_bit_cast(bf16x8, b), c, 0, 0, 0);
}

// ---------------------------------------------------------------------------
// P0: precompute Qhi/Qlo (row-major, split-bf16) and QT (transposed bf16 hi).
// blocks [0,512): 64x64 transpose tiles;  blocks [512,640): hi/lo planes.
// ---------------------------------------------------------------------------
__global__ void P0(const float* __restrict__ Qg, unsigned short* __restrict__ Qhi,
                   unsigned short* __restrict__ Qlo, unsigned short* __restrict__ QT)
{
  const int bid = blockIdx.x, tid = threadIdx.x;
  if (bid < 512) {
    __shared__ unsigned short t[64][68];
    const int b = bid >> 4;
    const int q0 = ((bid >> 2) & 3) * 64, d0 = (bid & 3) * 64;
    {
      const int qr = tid >> 2, dp = (tid & 3) * 16;
      const float* src = Qg + ((size_t)b * TQ + q0 + qr) * DD + d0 + dp;
#pragma unroll
      for (int i = 0; i < 16; i += 4) {
        float4v v = *(const float4v*)(src + i);
#pragma unroll
        for (int j = 0; j < 4; ++j) t[qr][dp + i + j] = f2bf(v[j]);
      }
    }
    __syncthreads();
    {
      const int dr = tid >> 2, qp = (tid & 3) * 16;
      us8 a, c;
#pragma unroll
      for (int i = 0; i < 8; ++i) a[i] = t[qp + i][dr];
#pragma unroll
      for (int i = 0; i < 8; ++i) c[i] = t[qp + 8 + i][dr];
      unsigned short* dst = QT + ((size_t)b * DD + d0 + dr) * TQ + q0 + qp;
      *(us8*)dst = a;
      *(us8*)(dst + 8) = c;
    }
  } else {
    const int id = bid - 512;                       // 0..127
    const size_t total = (size_t)NB * TQ * DD;      // 2M elements
    for (size_t base = ((size_t)id * 256 + tid) * 8; base < total;
         base += (size_t)128 * 256 * 8) {
      float v[8];
      *(float4v*)v = *(const float4v*)(Qg + base);
      *(float4v*)(v + 4) = *(const float4v*)(Qg + base + 4);
      us8 h, lo;
      split8(v, h, lo);
      *(us8*)(Qhi + base) = h;
      *(us8*)(Qlo + base) = lo;
    }
  }
}

// ---------------------------------------------------------------------------
// Kernel A: per (batch, 64-row c-tile). 256 threads = 4 waves, each wave owns
// a 64x64 q-chunk (sim) / d-chunk (PV). C tile staged ONCE in LDS (hi/lo,
// swizzled); B-operands (Qhi/Qlo/QT) read straight from global (L2-resident).
// Only 5 barriers in the whole kernel.
// ---------------------------------------------------------------------------
__global__ __launch_bounds__(256, 2)
void kA(const float* __restrict__ Cg, const unsigned short* __restrict__ Qhi,
        const unsigned short* __restrict__ Qlo, const unsigned short* __restrict__ QT,
        const int* __restrict__ clenp, const int* __restrict__ qlenp,
        float* __restrict__ out1, float* __restrict__ Mws)
{
  __shared__ __align__(16) char lds[66560];
  char* const bufChi = lds;                 // [64][512B] swizzled (later: P tile)
  char* const bufClo = lds + 32768;         // [64][512B] swizzled
  float* const red = (float*)(lds + 65536); // [4][64]
  char* const bufP = lds;

  const int bid = blockIdx.x;
  const int b = bid & 31;                   // batch -> fixed XCD (bid%8 == b%8)
  const int c0 = (bid >> 5) * CR;
  const int tid = threadIdx.x;
  const int l = tid & 63, wid = tid >> 6;
  const int g = l >> 4, lm = l & 15;
  const int clen = clenp[b], qlen = qlenp[b];

  const float* Cb = Cg + (size_t)(b * TC + c0) * DD;
  const unsigned short* Qhb = Qhi + (size_t)b * TQ * DD;
  const unsigned short* Qlb = Qlo + (size_t)b * TQ * DD;
  const unsigned short* QTb = QT + (size_t)b * DD * TQ;

  // ---- stage C tile once: 64 rows x 256 d fp32 -> hi/lo bf16 LDS ----
  {
    const int r = tid >> 2;
    const int d0 = (tid & 3) * 64;
    const float* src = Cb + (size_t)r * DD + d0;
#pragma unroll
    for (int i = 0; i < 8; ++i) {
      float v[8];
      *(float4v*)(v) = *(const float4v*)(src + i * 8);
      *(float4v*)(v + 4) = *(const float4v*)(src + i * 8 + 4);
      us8 h, lo;
      split8(v, h, lo);
      const int cb = (d0 + i * 8) * 2;
      *(us8*)(bufChi + r * 512 + swz(r, cb)) = h;
      *(us8*)(bufClo + r * 512 + swz(r, cb)) = lo;
    }
  }
  __syncthreads();   // barrier 1

  f32x4 acc[4][4];
#pragma unroll
  for (int mt = 0; mt < 4; ++mt)
#pragma unroll
    for (int nt = 0; nt < 4; ++nt) acc[mt][nt] = (f32x4)0.0f;

  // ---- sim: no barriers; A from LDS, B from global (L2) ----
#pragma unroll
  for (int kk = 0; kk < 8; ++kk) {
    us8 ah[4], al[4], bh[4], bl[4];
#pragma unroll
    for (int mt = 0; mt < 4; ++mt) {
      const int row = mt * 16 + lm;
      const int cb = kk * 64 + g * 16;
      ah[mt] = *(const us8*)(bufChi + row * 512 + swz(row, cb));
      al[mt] = *(const us8*)(bufClo + row * 512 + swz(row, cb));
    }
#pragma unroll
    for (int nt = 0; nt < 4; ++nt) {
      const size_t off = (size_t)(wid * 64 + nt * 16 + lm) * DD + kk * 32 + g * 8;
      bh[nt] = *(const us8*)(Qhb + off);
      bl[nt] = *(const us8*)(Qlb + off);
    }
#pragma unroll
    for (int mt = 0; mt < 4; ++mt)
#pragma unroll
      for (int nt = 0; nt < 4; ++nt) {
        acc[mt][nt] = mfma16(ah[mt], bh[nt], acc[mt][nt]);
        acc[mt][nt] = mfma16(ah[mt], bl[nt], acc[mt][nt]);
        acc[mt][nt] = mfma16(al[mt], bh[nt], acc[mt][nt]);
      }
  }

  // ---- mask (exact fp32 absorption to -1e29, as reference) ----
#pragma unroll
  for (int nt = 0; nt < 4; ++nt) {
    const int q = wid * 64 + nt * 16 + lm;
    const bool qm = q >= qlen;
#pragma unroll
    for (int mt = 0; mt < 4; ++mt)
#pragma unroll
      for (int j = 0; j < 4; ++j) {
        const int c = c0 + mt * 16 + g * 4 + j;
        if (qm || c >= clen) acc[mt][nt][j] = VNEG;
      }
  }

  // ---- softmax over q (wave-local shuffle + cross-wave LDS) ----
  float rmax[4][4], rsum[4][4];
#pragma unroll
  for (int mt = 0; mt < 4; ++mt)
#pragma unroll
    for (int j = 0; j < 4; ++j) {
      float m = fmaxf(fmaxf(acc[mt][0][j], acc[mt][1][j]),
                      fmaxf(acc[mt][2][j], acc[mt][3][j]));
      m = fmaxf(m, __shfl_xor(m, 1, 64));
      m = fmaxf(m, __shfl_xor(m, 2, 64));
      m = fmaxf(m, __shfl_xor(m, 4, 64));
      m = fmaxf(m, __shfl_xor(m, 8, 64));
      rmax[mt][j] = m;
    }
  if (lm == 0) {
#pragma unroll
    for (int mt = 0; mt < 4; ++mt)
#pragma unroll
      for (int j = 0; j < 4; ++j)
        red[wid * 64 + mt * 16 + g * 4 + j] = rmax[mt][j];
  }
  __syncthreads();   // barrier 2 (also fences all sim LDS reads before P write)
#pragma unroll
  for (int mt = 0; mt < 4; ++mt)
#pragma unroll
    for (int j = 0; j < 4; ++j) {
      const int row = mt * 16 + g * 4 + j;
      const float m = fmaxf(fmaxf(red[row], red[64 + row]),
                            fmaxf(red[128 + row], red[192 + row]));
      rmax[mt][j] = m;
      if (wid == 0 && lm == 0) Mws[b * TC + c0 + row] = m;
    }
  // exp + wave partial sums + write P (bf16, un-normalized) into dead C region
#pragma unroll
  for (int mt = 0; mt < 4; ++mt)
#pragma unroll
    for (int j = 0; j < 4; ++j) {
      float s = 0.f;
#pragma unroll
      for (int nt = 0; nt < 4; ++nt) {
        const float p = __expf(acc[mt][nt][j] - rmax[mt][j]);
        acc[mt][nt][j] = p;
        s += p;
      }
      s += __shfl_xor(s, 1, 64);
      s += __shfl_xor(s, 2, 64);
      s += __shfl_xor(s, 4, 64);
      s += __shfl_xor(s, 8, 64);
      rsum[mt][j] = s;
    }
#pragma unroll
  for (int mt = 0; mt < 4; ++mt)
#pragma unroll
    for (int nt = 0; nt < 4; ++nt)
#pragma unroll
      for (int j = 0; j < 4; ++j) {
        const int row = mt * 16 + g * 4 + j;
        const int cb = (wid * 64 + nt * 16 + lm) * 2;
        *(unsigned short*)(bufP + row * 512 + swz(row, cb)) = f2bf(acc[mt][nt][j]);
      }
  __syncthreads();   // barrier 3 (red max-reads done; P visible)
  if (lm == 0) {
#pragma unroll
    for (int mt = 0; mt < 4; ++mt)
#pragma unroll
      for (int j = 0; j < 4; ++j)
        red[wid * 64 + mt * 16 + g * 4 + j] = rsum[mt][j];
  }
  __syncthreads();   // barrier 4
#pragma unroll
  for (int mt = 0; mt < 4; ++mt)
#pragma unroll
    for (int j = 0; j < 4; ++j) {
      const int row = mt * 16 + g * 4 + j;
      rsum[mt][j] = (red[row] + red[64 + row]) + (red[128 + row] + red[192 + row]);
    }

  // ---- PV: out1 = P @ Q; A from LDS P, B from global QT (L2) ----
  f32x4 pacc[4][4];
#pragma unroll
  for (int mt = 0; mt < 4; ++mt)
#pragma unroll
    for (int dt = 0; dt < 4; ++dt) pacc[mt][dt] = (f32x4)0.0f;
#pragma unroll
  for (int kq = 0; kq < 8; ++kq) {
    us8 pa[4], qb[4];
#pragma unroll
    for (int mt = 0; mt < 4; ++mt) {
      const int row = mt * 16 + lm;
      pa[mt] = *(const us8*)(bufP + row * 512 + swz(row, kq * 64 + g * 16));
    }
#pragma unroll
    for (int dt = 0; dt < 4; ++dt) {
      const int d = wid * 64 + dt * 16 + lm;
      qb[dt] = *(const us8*)(QTb + (size_t)d * TQ + kq * 32 + g * 8);
    }
#pragma unroll
    for (int mt = 0; mt < 4; ++mt)
#pragma unroll
      for (int dt = 0; dt < 4; ++dt)
        pacc[mt][dt] = mfma16(pa[mt], qb[dt], pacc[mt][dt]);
  }

  // ---- epilogue ----
#pragma unroll
  for (int mt = 0; mt < 4; ++mt)
#pragma unroll
    for (int j = 0; j < 4; ++j) {
      const float inv = 1.0f / rsum[mt][j];
      const size_t rowoff = (size_t)(b * TC + c0 + mt * 16 + g * 4 + j) * DD;
#pragma unroll
      for (int dt = 0; dt < 4; ++dt)
        out1[rowoff + wid * 64 + dt * 16 + lm] = pacc[mt][dt][j] * inv;
    }
}

// ---------------------------------------------------------------------------
// Kernel B1: per-batch max + softmax denominator over M[b, 0..TC)
// ---------------------------------------------------------------------------
__global__ void kB1(const float* __restrict__ Mws, float* __restrict__ bmax,
                    float* __restrict__ bden)
{
  const int b = blockIdx.x, tid = threadIdx.x;
  __shared__ float sred[8];
  const float* Mb = Mws + b * TC;
  float m = -3.4e38f;
  for (int i = tid; i < TC; i += 256) m = fmaxf(m, Mb[i]);
  m = fmaxf(m, __shfl_xor(m, 1, 64));  m = fmaxf(m, __shfl_xor(m, 2, 64));
  m = fmaxf(m, __shfl_xor(m, 4, 64));  m = fmaxf(m, __shfl_xor(m, 8, 64));
  m = fmaxf(m, __shfl_xor(m, 16, 64)); m = fmaxf(m, __shfl_xor(m, 32, 64));
  const int w = tid >> 6;
  if ((tid & 63) == 0) sred[w] = m;
  __syncthreads();
  m = fmaxf(fmaxf(sred[0], sred[1]), fmaxf(sred[2], sred[3]));
  float s = 0.f;
  for (int i = tid; i < TC; i += 256) s += __expf(Mb[i] - m);
  s += __shfl_xor(s, 1, 64);  s += __shfl_xor(s, 2, 64);
  s += __shfl_xor(s, 4, 64);  s += __shfl_xor(s, 8, 64);
  s += __shfl_xor(s, 16, 64); s += __shfl_xor(s, 32, 64);
  if ((tid & 63) == 0) sred[4 + w] = s;
  __syncthreads();
  if (tid == 0) { bmax[b] = m; bden[b] = (sred[4] + sred[5]) + (sred[6] + sred[7]); }
}

// ---------------------------------------------------------------------------
// Kernel B2: part[b,chunk,d] = sum_{c in chunk} softmax(M)[c] * C[b,c,d]
// ---------------------------------------------------------------------------
__global__ void kB2(const float* __restrict__ Cg, const float* __restrict__ Mws,
                    const float* __restrict__ bmax, const float* __restrict__ bden,
                    float* __restrict__ part)
{
  const int b = blockIdx.x >> 4;
  const int ch = blockIdx.x & 15;
  const int cbase = ch * 128;
  const int tid = threadIdx.x;                // = d
  __shared__ float w[128];
  const float bm = bmax[b];
  const float invd = 1.0f / bden[b];
  if (tid < 128) w[tid] = __expf(Mws[b * TC + cbase + tid] - bm) * invd;
  __syncthreads();
  float acc = 0.f;
  const float* Cb = Cg + (size_t)(b * TC + cbase) * DD + tid;
#pragma unroll 4
  for (int c = 0; c < 128; ++c) acc += w[c] * Cb[(size_t)c * DD];
  part[((size_t)b * 16 + ch) * DD + tid] = acc;
}

// ---------------------------------------------------------------------------
// Kernel C (fused B3): q2c[b,d] = sum_ch part, broadcast -> out2[b, c-seg, d]
// ---------------------------------------------------------------------------
__global__ void kC(const float* __restrict__ part, float* __restrict__ out2)
{
  const int b = blockIdx.x >> 4, seg = blockIdx.x & 15;
  const int d = threadIdx.x;
  float s = 0.f;
#pragma unroll
  for (int ch = 0; ch < 16; ++ch) s += part[((size_t)b * 16 + ch) * DD + d];
  float* dst = out2 + ((size_t)b * TC + seg * 128) * DD + d;
#pragma unroll 4
  for (int c = 0; c < 128; ++c) dst[(size_t)c * DD] = s;
}

extern "C" void kernel_launch(void* const* d_in, const int* in_sizes, int n_in,
                              void* d_out, int out_size, void* d_ws, size_t ws_size,
                              hipStream_t stream)
{
  const float* Cg = (const float*)d_in[0];
  const float* Qg = (const float*)d_in[1];
  const int* clen = (const int*)d_in[2];
  const int* qlen = (const int*)d_in[3];
  float* out1 = (float*)d_out;
  float* out2 = out1 + (size_t)NB * TC * DD;

  char* ws = (char*)d_ws;
  float* Mws  = (float*)(ws);                         // 32*2048 f32   = 256 KB
  float* part = (float*)(ws + 262144);                // 32*16*256 f32 = 512 KB
  float* bmax = (float*)(ws + 786432);                // 32 f32
  float* bden = (float*)(ws + 786560);                // 32 f32
  unsigned short* Qhi = (unsigned short*)(ws + 786688);        // 4 MB
  unsigned short* Qlo = (unsigned short*)(ws + 786688 + 4194304);
  unsigned short* QT  = (unsigned short*)(ws + 786688 + 8388608);

  P0 <<<dim3(640), dim3(256), 0, stream>>>(Qg, Qhi, Qlo, QT);
  kA <<<dim3(NB * (TC / CR)), dim3(256), 0, stream>>>(Cg, Qhi, Qlo, QT, clen, qlen,
                                                      out1, Mws);
  kB1<<<dim3(NB), dim3(256), 0, stream>>>(Mws, bmax, bden);
  kB2<<<dim3(NB * 16), dim3(256), 0, stream>>>(Cg, Mws, bmax, bden, part);
  kC <<<dim3(NB * 16), dim3(256), 0, stream>>>(part, out2);
}